// Round 5
// baseline (3428.326 us; speedup 1.0000x reference)
//
#include <hip/hip_runtime.h>
#include <hip/hip_bf16.h>

#define NN 10000
#define NE 640000
#define SD 128
#define HD1 60
#define HD2 30
#define CONCAT 10003
#define ACT 10000
#define GRID 512
#define BS 256
#define NTH (GRID * BS)

typedef unsigned int u32;
typedef unsigned short u16;
typedef u16 u16x8 __attribute__((ext_vector_type(8)));
typedef float f32x4 __attribute__((ext_vector_type(4)));

__device__ __forceinline__ float bf2f_bits(u16 u) {
    return __uint_as_float(((u32)u) << 16);
}
__device__ __forceinline__ float loadF(const void* base, long idx, int bf) {
    if (bf) return bf2f_bits(((const u16*)base)[idx]);
    return ((const float*)base)[idx];
}
__device__ __forceinline__ int loadI(const void* base, long idx, int i64) {
    if (i64) return (int)((const long long*)base)[idx];
    return ((const int*)base)[idx];
}

// ---- poison-tolerant grid barrier: per-barrier sequence numbers, no init ----
__device__ __forceinline__ void gbar(int* barf, int* bargo, int seq) {
    __syncthreads();
    __threadfence();
    if (threadIdx.x == 0)
        __hip_atomic_store(&barf[blockIdx.x], seq, __ATOMIC_RELEASE, __HIP_MEMORY_SCOPE_AGENT);
    if (blockIdx.x == 0) {
        __shared__ int sdone;
        int it = 0;
        while (true) {
            if (threadIdx.x == 0) sdone = 1;
            __syncthreads();
            int v1 = __hip_atomic_load(&barf[threadIdx.x], __ATOMIC_ACQUIRE, __HIP_MEMORY_SCOPE_AGENT);
            int v2 = __hip_atomic_load(&barf[threadIdx.x + 256], __ATOMIC_ACQUIRE, __HIP_MEMORY_SCOPE_AGENT);
            if (v1 != seq || v2 != seq) sdone = 0;
            __syncthreads();
            if (sdone != 0 || ++it > (1 << 19)) break;
            __builtin_amdgcn_s_sleep(2);
        }
        if (threadIdx.x == 0)
            __hip_atomic_store(bargo, seq, __ATOMIC_RELEASE, __HIP_MEMORY_SCOPE_AGENT);
    } else if (threadIdx.x == 0) {
        int it = 0;
        while (__hip_atomic_load(bargo, __ATOMIC_ACQUIRE, __HIP_MEMORY_SCOPE_AGENT) != seq) {
            if (++it > (1 << 20)) break;
            __builtin_amdgcn_s_sleep(2);
        }
    }
    __syncthreads();
    __threadfence();
}

__global__ void __launch_bounds__(BS, 4) mega(
    const void* __restrict__ x_in, const void* __restrict__ edge,
    const void* sc0, const void* sc1, const void* sc2,
    const void* __restrict__ W1, const void* __restrict__ b1,
    const void* __restrict__ W2, const void* __restrict__ b2,
    const void* __restrict__ W3, const void* __restrict__ b3,
    const void* __restrict__ Wa, const void* __restrict__ ba,
    const void* __restrict__ Wc, const void* __restrict__ bc,
    int* barf, int* bargo, int* __restrict__ deg, float* __restrict__ dinv,
    int* __restrict__ row_ptr, int* __restrict__ fillp, int2* __restrict__ csr,
    float* __restrict__ X0, float* __restrict__ T1, float* __restrict__ H1,
    float* __restrict__ H2, float* __restrict__ Wt1, float* __restrict__ Wt2,
    float* __restrict__ Wt3, float* __restrict__ state, void* __restrict__ out) {
    __shared__ int sflags[2];
    __shared__ int scan_lds[BS];
    __shared__ __align__(16) float sA[2][SD], sB[2][SD], sC[2][SD];
    __shared__ __align__(16) float tA[4][64], tB[4][64], tC[4][64];

    const int tid = threadIdx.x, gid = blockIdx.x;
    const int gtid = gid * BS + tid;

    // per-block dtype probe (redundant across blocks -> no sync dependency)
    if (tid == 0) {
        const int* e32 = (const int*)edge;
        int cnt64 = 0;
        for (int e = 0; e < 64; ++e) {
            int lo = e32[2 * e], hi = e32[2 * e + 1];
            if (hi == 0 && lo >= 0 && lo < NN) cnt64++;
        }
        sflags[0] = (cnt64 >= 56) ? 1 : 0;
        const u32* w = (const u32*)Wa;
        int c = 0;
        for (int j = 0; j < 256; ++j) {
            u32 lo = w[j] & 0xFFFFu;
            int ex = (int)((lo >> 7) & 0xFF);
            if (ex >= 100 && ex <= 140) c++;
        }
        sflags[1] = (c >= 128) ? 1 : 0;
    }
    __syncthreads();
    const int i64f = sflags[0], bf = sflags[1];

    // ---- S0: zero deg, loadx -> X0 (f32), transpose weights -> Wt ----
    for (int i = gtid; i < NN; i += NTH) deg[i] = 0;
    for (int i = gtid; i < NN * SD / 8; i += NTH) {
        float v[8];
        if (bf) {
            u16x8 u = ((const u16x8*)x_in)[i];
#pragma unroll
            for (int j = 0; j < 8; ++j) v[j] = bf2f_bits(u[j]);
        } else {
            f32x4 a = ((const f32x4*)x_in)[2 * i];
            f32x4 b = ((const f32x4*)x_in)[2 * i + 1];
#pragma unroll
            for (int j = 0; j < 4; ++j) { v[j] = a[j]; v[4 + j] = b[j]; }
        }
        f32x4* o = (f32x4*)(X0 + 8 * (long)i);
        o[0] = (f32x4){v[0], v[1], v[2], v[3]};
        o[1] = (f32x4){v[4], v[5], v[6], v[7]};
    }
    const int WT_N = 3 * SD * HD1 + 3 * HD1 * HD2 + 3 * HD2;
    for (int t = gtid; t < WT_N; t += NTH) {
        if (t < 3 * SD * HD1) {
            int k = t / (SD * HD1), r = t % (SD * HD1);
            int j = r / HD1, o = r % HD1;
            Wt1[(k * HD1 + o) * SD + j] = loadF(W1, t, bf);
        } else if (t < 3 * SD * HD1 + 3 * HD1 * HD2) {
            int t2 = t - 3 * SD * HD1;
            int k = t2 / (HD1 * HD2), r = t2 % (HD1 * HD2);
            int j = r / HD2, o = r % HD2;
            Wt2[(k * HD2 + o) * HD1 + j] = loadF(W2, t2, bf);
        } else {
            int t3 = t - 3 * SD * HD1 - 3 * HD1 * HD2;
            Wt3[t3] = loadF(W3, t3, bf);
        }
    }
    gbar(barf, bargo, 1);

    // ---- S1: degree histogram ----
    for (int e = gtid; e < NE; e += NTH)
        atomicAdd(&deg[loadI(edge, NE + e, i64f)], 1);
    gbar(barf, bargo, 2);

    // ---- S2: dinv (all blocks) + exclusive scan (block 0) ----
    for (int i = gtid; i < NN; i += NTH) {
        int d = deg[i];
        dinv[i] = d > 0 ? rsqrtf((float)d) : 0.f;
    }
    if (gid == 0) {
        const int CH = 40;  // 256*40 = 10240 >= NN
        int base = tid * CH;
        int ssum = 0;
        for (int j = 0; j < CH; ++j) {
            int idx = base + j;
            if (idx < NN) ssum += deg[idx];
        }
        scan_lds[tid] = ssum;
        __syncthreads();
        for (int off = 1; off < BS; off <<= 1) {
            int t = (tid >= off) ? scan_lds[tid - off] : 0;
            __syncthreads();
            scan_lds[tid] += t;
            __syncthreads();
        }
        int run = (tid > 0) ? scan_lds[tid - 1] : 0;
        for (int j = 0; j < CH; ++j) {
            int idx = base + j;
            if (idx < NN) {
                row_ptr[idx] = run;
                fillp[idx] = run;
                run += deg[idx];
            }
        }
        if (tid == 255) row_ptr[NN] = scan_lds[255];
    }
    gbar(barf, bargo, 3);

    // ---- S3: CSR fill ----
    for (int e = gtid; e < NE; e += NTH) {
        int s = loadI(edge, e, i64f);
        int d = loadI(edge, NE + e, i64f);
        int pos = atomicAdd(&fillp[d], 1);
        int2 rec;
        rec.x = s;
        rec.y = __float_as_int(-dinv[s] * dinv[d]);
        csr[pos] = rec;
    }
    gbar(barf, bargo, 4);

    // ---- S4: T1 = Lhat X0   (128-thread groups, group per row) ----
    {
        int g = gtid >> 7, l = gtid & 127;
        for (int r = g; r < NN; r += NTH / 128) {
            int beg = row_ptr[r], end = row_ptr[r + 1];
            float acc = 0.f;
            int p = beg;
            for (; p + 3 < end; p += 4) {
                int2 e0 = csr[p], e1 = csr[p + 1], e2 = csr[p + 2], e3 = csr[p + 3];
                acc += __int_as_float(e0.y) * X0[(long)e0.x * SD + l] +
                       __int_as_float(e1.y) * X0[(long)e1.x * SD + l] +
                       __int_as_float(e2.y) * X0[(long)e2.x * SD + l] +
                       __int_as_float(e3.y) * X0[(long)e3.x * SD + l];
            }
            for (; p < end; ++p) {
                int2 e = csr[p];
                acc += __int_as_float(e.y) * X0[(long)e.x * SD + l];
            }
            T1[(long)r * SD + l] = acc;
        }
    }
    gbar(barf, bargo, 5);

    // ---- S5: T2 row (LDS) + cheb1 projection -> H1  (uniform 10 iters) ----
    {
        int half = tid >> 7, l = tid & 127;
        int g = gid * 2 + half;
        for (int it = 0; it < 10; ++it) {
            int r = g + it * 1024;
            bool act = r < NN;
            if (act) {
                float a0 = X0[(long)r * SD + l];
                sA[half][l] = a0;
                sB[half][l] = T1[(long)r * SD + l];
                int beg = row_ptr[r], end = row_ptr[r + 1];
                float acc = 0.f;
                int p = beg;
                for (; p + 3 < end; p += 4) {
                    int2 e0 = csr[p], e1 = csr[p + 1], e2 = csr[p + 2], e3 = csr[p + 3];
                    acc += __int_as_float(e0.y) * T1[(long)e0.x * SD + l] +
                           __int_as_float(e1.y) * T1[(long)e1.x * SD + l] +
                           __int_as_float(e2.y) * T1[(long)e2.x * SD + l] +
                           __int_as_float(e3.y) * T1[(long)e3.x * SD + l];
                }
                for (; p < end; ++p) {
                    int2 e = csr[p];
                    acc += __int_as_float(e.y) * T1[(long)e.x * SD + l];
                }
                sC[half][l] = 2.f * acc - a0;
            }
            __syncthreads();
            if (act && l < HD1) {
                const f32x4* Av = (const f32x4*)sA[half];
                const f32x4* Bv = (const f32x4*)sB[half];
                const f32x4* Cv = (const f32x4*)sC[half];
                const f32x4* w0 = (const f32x4*)(Wt1 + (0 * HD1 + l) * SD);
                const f32x4* w1 = (const f32x4*)(Wt1 + (1 * HD1 + l) * SD);
                const f32x4* w2 = (const f32x4*)(Wt1 + (2 * HD1 + l) * SD);
                float acc = loadF(b1, l, bf);
#pragma unroll 4
                for (int jq = 0; jq < SD / 4; ++jq) {
                    f32x4 a = Av[jq], bb = Bv[jq], c = Cv[jq];
                    f32x4 x0 = w0[jq], x1 = w1[jq], x2 = w2[jq];
#pragma unroll
                    for (int q = 0; q < 4; ++q)
                        acc += a[q] * x0[q] + bb[q] * x1[q] + c[q] * x2[q];
                }
                H1[(long)r * HD1 + l] = tanhf(acc);
            }
            __syncthreads();
        }
    }
    gbar(barf, bargo, 6);

    // ---- S6: U1 = Lhat H1 -> T1 (60-stride) ----
    {
        int g = gtid >> 6, l = gtid & 63;
        if (l < HD1) {
            for (int r = g; r < NN; r += NTH / 64) {
                int beg = row_ptr[r], end = row_ptr[r + 1];
                float acc = 0.f;
                int p = beg;
                for (; p + 3 < end; p += 4) {
                    int2 e0 = csr[p], e1 = csr[p + 1], e2 = csr[p + 2], e3 = csr[p + 3];
                    acc += __int_as_float(e0.y) * H1[(long)e0.x * HD1 + l] +
                           __int_as_float(e1.y) * H1[(long)e1.x * HD1 + l] +
                           __int_as_float(e2.y) * H1[(long)e2.x * HD1 + l] +
                           __int_as_float(e3.y) * H1[(long)e3.x * HD1 + l];
                }
                for (; p < end; ++p) {
                    int2 e = csr[p];
                    acc += __int_as_float(e.y) * H1[(long)e.x * HD1 + l];
                }
                T1[(long)r * HD1 + l] = acc;
            }
        }
    }
    gbar(barf, bargo, 7);

    // ---- S7: T2' (LDS) + cheb2 -> H2  (uniform 5 iters, 64-thread groups) ----
    {
        int q4 = tid >> 6, l = tid & 63;
        int g = gid * 4 + q4;
        for (int it = 0; it < 5; ++it) {
            int r = g + it * 2048;
            bool act = r < NN;
            if (act && l < HD1) {
                float a0 = H1[(long)r * HD1 + l];
                tA[q4][l] = a0;
                tB[q4][l] = T1[(long)r * HD1 + l];
                int beg = row_ptr[r], end = row_ptr[r + 1];
                float acc = 0.f;
                int p = beg;
                for (; p + 3 < end; p += 4) {
                    int2 e0 = csr[p], e1 = csr[p + 1], e2 = csr[p + 2], e3 = csr[p + 3];
                    acc += __int_as_float(e0.y) * T1[(long)e0.x * HD1 + l] +
                           __int_as_float(e1.y) * T1[(long)e1.x * HD1 + l] +
                           __int_as_float(e2.y) * T1[(long)e2.x * HD1 + l] +
                           __int_as_float(e3.y) * T1[(long)e3.x * HD1 + l];
                }
                for (; p < end; ++p) {
                    int2 e = csr[p];
                    acc += __int_as_float(e.y) * T1[(long)e.x * HD1 + l];
                }
                tC[q4][l] = 2.f * acc - a0;
            }
            __syncthreads();
            if (act && l < HD2) {
                const f32x4* Av = (const f32x4*)tA[q4];
                const f32x4* Bv = (const f32x4*)tB[q4];
                const f32x4* Cv = (const f32x4*)tC[q4];
                const f32x4* w0 = (const f32x4*)(Wt2 + (0 * HD2 + l) * HD1);
                const f32x4* w1 = (const f32x4*)(Wt2 + (1 * HD2 + l) * HD1);
                const f32x4* w2 = (const f32x4*)(Wt2 + (2 * HD2 + l) * HD1);
                float acc = loadF(b2, l, bf);
#pragma unroll
                for (int jq = 0; jq < HD1 / 4; ++jq) {
                    f32x4 a = Av[jq], bb = Bv[jq], c = Cv[jq];
                    f32x4 x0 = w0[jq], x1 = w1[jq], x2 = w2[jq];
#pragma unroll
                    for (int q = 0; q < 4; ++q)
                        acc += a[q] * x0[q] + bb[q] * x1[q] + c[q] * x2[q];
                }
                H2[(long)r * HD2 + l] = tanhf(acc);
            }
            __syncthreads();
        }
    }
    gbar(barf, bargo, 8);

    // ---- S8: V1 = Lhat H2 -> T1 (30-stride) ----
    {
        int g = gtid >> 5, l = gtid & 31;
        if (l < HD2) {
            for (int r = g; r < NN; r += NTH / 32) {
                int beg = row_ptr[r], end = row_ptr[r + 1];
                float acc = 0.f;
                for (int p = beg; p < end; ++p) {
                    int2 e = csr[p];
                    acc += __int_as_float(e.y) * H2[(long)e.x * HD2 + l];
                }
                T1[(long)r * HD2 + l] = acc;
            }
        }
    }
    gbar(barf, bargo, 9);

    // ---- S9: V2 + cheb3 -> state[0..9999]; tail scalars ----
    {
        int g = gtid >> 5, l = gtid & 31;
        for (int r = g; r < NN; r += NTH / 32) {
            float contrib = 0.f;
            if (l < HD2) {
                float t0 = H2[(long)r * HD2 + l];
                float t1v = T1[(long)r * HD2 + l];
                int beg = row_ptr[r], end = row_ptr[r + 1];
                float acc = 0.f;
                for (int p = beg; p < end; ++p) {
                    int2 e = csr[p];
                    acc += __int_as_float(e.y) * T1[(long)e.x * HD2 + l];
                }
                float t2 = 2.f * acc - t0;
                contrib = t0 * Wt3[l] + t1v * Wt3[HD2 + l] + t2 * Wt3[2 * HD2 + l];
            }
#pragma unroll
            for (int m = 16; m; m >>= 1) contrib += __shfl_xor(contrib, m, 32);
            if (l == 0) state[r] = tanhf(contrib + loadF(b3, 0, bf));
        }
        if (gtid == 0) {
            state[10000] = loadF(sc0, 0, bf);
            state[10001] = loadF(sc1, 0, bf);
            state[10002] = loadF(sc2, 0, bf);
        }
    }
    gbar(barf, bargo, 10);

    // ---- S10: heads (wave per row, grid-stride) ----
    {
        int wv = gtid >> 6, lane = tid & 63;
        for (int r = wv; r <= ACT; r += NTH / 64) {
            long base = (r < ACT) ? (long)r * CONCAT : 0;
            const void* wb = (r < ACT) ? Wa : Wc;
            float acc = 0.f;
            if (bf) {
                const u16* w = (const u16*)wb + base;
                int k = (int)((16 - ((2 * base) & 15)) & 15) >> 1;
                for (int i = lane; i < k; i += 64) acc += state[i] * bf2f_bits(w[i]);
                int nv = (CONCAT - k) >> 3;
                const u16x8* wvp = (const u16x8*)(w + k);
                for (int v = lane; v < nv; v += 64) {
                    u16x8 ww = wvp[v];
                    int ib = k + v * 8;
#pragma unroll
                    for (int j = 0; j < 8; ++j) acc += state[ib + j] * bf2f_bits(ww[j]);
                }
                for (int i = k + nv * 8 + lane; i < CONCAT; i += 64)
                    acc += state[i] * bf2f_bits(w[i]);
            } else {
                const float* w = (const float*)wb + base;
                int k = (int)((16 - ((4 * base) & 15)) & 15) >> 2;
                for (int i = lane; i < k; i += 64) acc += state[i] * w[i];
                int nv = (CONCAT - k) >> 2;
                const f32x4* wvp = (const f32x4*)(w + k);
                for (int v = lane; v < nv; v += 64) {
                    f32x4 ww = wvp[v];
                    int ib = k + v * 4;
#pragma unroll
                    for (int j = 0; j < 4; ++j) acc += state[ib + j] * ww[j];
                }
                for (int i = k + nv * 4 + lane; i < CONCAT; i += 64)
                    acc += state[i] * w[i];
            }
#pragma unroll
            for (int o = 32; o > 0; o >>= 1) acc += __shfl_xor(acc, o);
            if (lane == 0) {
                float bias = (r < ACT) ? loadF(ba, r, bf) : loadF(bc, 0, bf);
                float v = acc + bias;
                if (bf) ((__hip_bfloat16*)out)[r] = __float2bfloat16(v);
                else ((float*)out)[r] = v;
            }
        }
    }
}

extern "C" void kernel_launch(void* const* d_in, const int* in_sizes, int n_in,
                              void* d_out, int out_size, void* d_ws, size_t ws_size,
                              hipStream_t stream) {
    char* p = (char*)d_ws;
    auto alloc = [&](size_t bytes) {
        char* r = p;
        p += (bytes + 255) & ~(size_t)255;
        return (void*)r;
    };
    int* barf = (int*)alloc(GRID * 4);
    int* bargo = (int*)alloc(4);
    int* deg = (int*)alloc(NN * 4);
    float* dinv = (float*)alloc(NN * 4);
    int* row_ptr = (int*)alloc((NN + 1) * 4);
    int* fillp = (int*)alloc(NN * 4);
    int2* csr = (int2*)alloc((size_t)NE * 8);
    float* X0 = (float*)alloc((size_t)NN * SD * 4);
    float* T1 = (float*)alloc((size_t)NN * SD * 4);
    float* H1 = (float*)alloc((size_t)NN * HD1 * 4);
    float* H2 = (float*)alloc((size_t)NN * HD2 * 4);
    float* Wt1 = (float*)alloc(3 * SD * HD1 * 4);
    float* Wt2 = (float*)alloc(3 * HD1 * HD2 * 4);
    float* Wt3 = (float*)alloc(3 * HD2 * 4);
    float* state = (float*)alloc(CONCAT * 4);

    mega<<<GRID, BS, 0, stream>>>(
        d_in[0], d_in[1], d_in[2], d_in[3], d_in[4], d_in[5], d_in[6], d_in[7],
        d_in[8], d_in[9], d_in[10], d_in[11], d_in[12], d_in[13], d_in[14],
        barf, bargo, deg, dinv, row_ptr, fillp, csr, X0, T1, H1, H2,
        Wt1, Wt2, Wt3, state, d_out);
}

// Round 6
// 895.703 us; speedup vs baseline: 3.8275x; 3.8275x over previous
//
#include <hip/hip_runtime.h>
#include <hip/hip_bf16.h>

#define NN 10000
#define NE 640000
#define SD 128
#define HD1 60
#define HD2 30
#define CONCAT 10003
#define ACT 10000
#define GRID 512
#define BS 256
#define NTH (GRID * BS)

typedef unsigned int u32;
typedef unsigned short u16;
typedef u16 u16x8 __attribute__((ext_vector_type(8)));
typedef float f32x4 __attribute__((ext_vector_type(4)));

__device__ __forceinline__ float bf2f_bits(u16 u) {
    return __uint_as_float(((u32)u) << 16);
}
__device__ __forceinline__ float loadF(const void* base, long idx, int bf) {
    if (bf) return bf2f_bits(((const u16*)base)[idx]);
    return ((const float*)base)[idx];
}
__device__ __forceinline__ int loadI(const void* base, long idx, int i64) {
    if (i64) return (int)((const long long*)base)[idx];
    return ((const int*)base)[idx];
}

// ---- poison-tolerant grid barrier, relaxed polling + single fences ----
// Protocol: block b stores barf[b]=seq (relaxed). Block 0 scans all flags with
// relaxed loads; when all==seq it stores bargo=seq. Waiters poll bargo relaxed.
// Data visibility: ONE release fence (wbL2) before flag store, ONE acquire
// fence (invL2/L1) after go observed. No cache ops inside the spin loops.
__device__ __forceinline__ void gbar(int* barf, int* bargo, int seq) {
    __syncthreads();
    if (threadIdx.x == 0) {
        __builtin_amdgcn_fence(__ATOMIC_RELEASE, "agent");  // writeback this XCD's L2
        __hip_atomic_store(&barf[blockIdx.x], seq, __ATOMIC_RELAXED, __HIP_MEMORY_SCOPE_AGENT);
    }
    if (blockIdx.x == 0) {
        __shared__ int sdone;
        int it = 0;
        while (true) {
            if (threadIdx.x == 0) sdone = 1;
            __syncthreads();
            int ok = 1;
            for (int b = threadIdx.x; b < GRID; b += BS) {
                int v = __hip_atomic_load(&barf[b], __ATOMIC_RELAXED, __HIP_MEMORY_SCOPE_AGENT);
                if (v != seq) ok = 0;
            }
            if (!ok) sdone = 0;
            __syncthreads();
            if (sdone != 0 || ++it > (1 << 22)) break;
            __builtin_amdgcn_s_sleep(4);
        }
        if (threadIdx.x == 0)
            __hip_atomic_store(bargo, seq, __ATOMIC_RELAXED, __HIP_MEMORY_SCOPE_AGENT);
    } else if (threadIdx.x == 0) {
        int it = 0;
        while (__hip_atomic_load(bargo, __ATOMIC_RELAXED, __HIP_MEMORY_SCOPE_AGENT) != seq) {
            if (++it > (1 << 22)) break;
            __builtin_amdgcn_s_sleep(8);
        }
    }
    if (threadIdx.x == 0)
        __builtin_amdgcn_fence(__ATOMIC_ACQUIRE, "agent");  // invalidate stale L1/L2
    __syncthreads();
}

__global__ void __launch_bounds__(BS, 4) mega(
    const void* __restrict__ x_in, const void* __restrict__ edge,
    const void* sc0, const void* sc1, const void* sc2,
    const void* __restrict__ W1, const void* __restrict__ b1,
    const void* __restrict__ W2, const void* __restrict__ b2,
    const void* __restrict__ W3, const void* __restrict__ b3,
    const void* __restrict__ Wa, const void* __restrict__ ba,
    const void* __restrict__ Wc, const void* __restrict__ bc,
    int* barf, int* bargo, int* __restrict__ deg, float* __restrict__ dinv,
    int* __restrict__ row_ptr, int* __restrict__ fillp, int2* __restrict__ csr,
    float* __restrict__ X0, float* __restrict__ T1, float* __restrict__ H1,
    float* __restrict__ H2, float* __restrict__ Wt1, float* __restrict__ Wt2,
    float* __restrict__ Wt3, float* __restrict__ state, void* __restrict__ out) {
    __shared__ int sflags[2];
    __shared__ int scan_lds[BS];
    __shared__ __align__(16) float sA[2][SD], sB[2][SD], sC[2][SD];
    __shared__ __align__(16) float tA[4][64], tB[4][64], tC[4][64];

    const int tid = threadIdx.x, gid = blockIdx.x;
    const int gtid = gid * BS + tid;

    // per-block dtype probe (redundant across blocks -> no sync dependency)
    if (tid == 0) {
        const int* e32 = (const int*)edge;
        int cnt64 = 0;
        for (int e = 0; e < 64; ++e) {
            int lo = e32[2 * e], hi = e32[2 * e + 1];
            if (hi == 0 && lo >= 0 && lo < NN) cnt64++;
        }
        sflags[0] = (cnt64 >= 56) ? 1 : 0;
        const u32* w = (const u32*)Wa;
        int c = 0;
        for (int j = 0; j < 256; ++j) {
            u32 lo = w[j] & 0xFFFFu;
            int ex = (int)((lo >> 7) & 0xFF);
            if (ex >= 100 && ex <= 140) c++;
        }
        sflags[1] = (c >= 128) ? 1 : 0;
    }
    __syncthreads();
    const int i64f = sflags[0], bf = sflags[1];

    // ---- S0: zero deg, loadx -> X0 (f32), transpose weights -> Wt ----
    for (int i = gtid; i < NN; i += NTH) deg[i] = 0;
    for (int i = gtid; i < NN * SD / 8; i += NTH) {
        float v[8];
        if (bf) {
            u16x8 u = ((const u16x8*)x_in)[i];
#pragma unroll
            for (int j = 0; j < 8; ++j) v[j] = bf2f_bits(u[j]);
        } else {
            f32x4 a = ((const f32x4*)x_in)[2 * i];
            f32x4 b = ((const f32x4*)x_in)[2 * i + 1];
#pragma unroll
            for (int j = 0; j < 4; ++j) { v[j] = a[j]; v[4 + j] = b[j]; }
        }
        f32x4* o = (f32x4*)(X0 + 8 * (long)i);
        o[0] = (f32x4){v[0], v[1], v[2], v[3]};
        o[1] = (f32x4){v[4], v[5], v[6], v[7]};
    }
    const int WT_N = 3 * SD * HD1 + 3 * HD1 * HD2 + 3 * HD2;
    for (int t = gtid; t < WT_N; t += NTH) {
        if (t < 3 * SD * HD1) {
            int k = t / (SD * HD1), r = t % (SD * HD1);
            int j = r / HD1, o = r % HD1;
            Wt1[(k * HD1 + o) * SD + j] = loadF(W1, t, bf);
        } else if (t < 3 * SD * HD1 + 3 * HD1 * HD2) {
            int t2 = t - 3 * SD * HD1;
            int k = t2 / (HD1 * HD2), r = t2 % (HD1 * HD2);
            int j = r / HD2, o = r % HD2;
            Wt2[(k * HD2 + o) * HD1 + j] = loadF(W2, t2, bf);
        } else {
            int t3 = t - 3 * SD * HD1 - 3 * HD1 * HD2;
            Wt3[t3] = loadF(W3, t3, bf);
        }
    }
    gbar(barf, bargo, 1);

    // ---- S1: degree histogram ----
    for (int e = gtid; e < NE; e += NTH)
        atomicAdd(&deg[loadI(edge, NE + e, i64f)], 1);
    gbar(barf, bargo, 2);

    // ---- S2: dinv (all blocks) + exclusive scan (block 0) ----
    for (int i = gtid; i < NN; i += NTH) {
        int d = deg[i];
        dinv[i] = d > 0 ? rsqrtf((float)d) : 0.f;
    }
    if (gid == 0) {
        const int CH = 40;  // 256*40 = 10240 >= NN
        int base = tid * CH;
        int ssum = 0;
        for (int j = 0; j < CH; ++j) {
            int idx = base + j;
            if (idx < NN) ssum += deg[idx];
        }
        scan_lds[tid] = ssum;
        __syncthreads();
        for (int off = 1; off < BS; off <<= 1) {
            int t = (tid >= off) ? scan_lds[tid - off] : 0;
            __syncthreads();
            scan_lds[tid] += t;
            __syncthreads();
        }
        int run = (tid > 0) ? scan_lds[tid - 1] : 0;
        for (int j = 0; j < CH; ++j) {
            int idx = base + j;
            if (idx < NN) {
                row_ptr[idx] = run;
                fillp[idx] = run;
                run += deg[idx];
            }
        }
        if (tid == 255) row_ptr[NN] = scan_lds[255];
    }
    gbar(barf, bargo, 3);

    // ---- S3: CSR fill ----
    for (int e = gtid; e < NE; e += NTH) {
        int s = loadI(edge, e, i64f);
        int d = loadI(edge, NE + e, i64f);
        int pos = atomicAdd(&fillp[d], 1);
        int2 rec;
        rec.x = s;
        rec.y = __float_as_int(-dinv[s] * dinv[d]);
        csr[pos] = rec;
    }
    gbar(barf, bargo, 4);

    // ---- S4: T1 = Lhat X0   (128-thread groups, group per row) ----
    {
        int g = gtid >> 7, l = gtid & 127;
        for (int r = g; r < NN; r += NTH / 128) {
            int beg = row_ptr[r], end = row_ptr[r + 1];
            float acc = 0.f;
            int p = beg;
            for (; p + 3 < end; p += 4) {
                int2 e0 = csr[p], e1 = csr[p + 1], e2 = csr[p + 2], e3 = csr[p + 3];
                acc += __int_as_float(e0.y) * X0[(long)e0.x * SD + l] +
                       __int_as_float(e1.y) * X0[(long)e1.x * SD + l] +
                       __int_as_float(e2.y) * X0[(long)e2.x * SD + l] +
                       __int_as_float(e3.y) * X0[(long)e3.x * SD + l];
            }
            for (; p < end; ++p) {
                int2 e = csr[p];
                acc += __int_as_float(e.y) * X0[(long)e.x * SD + l];
            }
            T1[(long)r * SD + l] = acc;
        }
    }
    gbar(barf, bargo, 5);

    // ---- S5: T2 row (LDS) + cheb1 projection -> H1  (uniform 10 iters) ----
    {
        int half = tid >> 7, l = tid & 127;
        int g = gid * 2 + half;
        for (int it = 0; it < 10; ++it) {
            int r = g + it * 1024;
            bool act = r < NN;
            if (act) {
                float a0 = X0[(long)r * SD + l];
                sA[half][l] = a0;
                sB[half][l] = T1[(long)r * SD + l];
                int beg = row_ptr[r], end = row_ptr[r + 1];
                float acc = 0.f;
                int p = beg;
                for (; p + 3 < end; p += 4) {
                    int2 e0 = csr[p], e1 = csr[p + 1], e2 = csr[p + 2], e3 = csr[p + 3];
                    acc += __int_as_float(e0.y) * T1[(long)e0.x * SD + l] +
                           __int_as_float(e1.y) * T1[(long)e1.x * SD + l] +
                           __int_as_float(e2.y) * T1[(long)e2.x * SD + l] +
                           __int_as_float(e3.y) * T1[(long)e3.x * SD + l];
                }
                for (; p < end; ++p) {
                    int2 e = csr[p];
                    acc += __int_as_float(e.y) * T1[(long)e.x * SD + l];
                }
                sC[half][l] = 2.f * acc - a0;
            }
            __syncthreads();
            if (act && l < HD1) {
                const f32x4* Av = (const f32x4*)sA[half];
                const f32x4* Bv = (const f32x4*)sB[half];
                const f32x4* Cv = (const f32x4*)sC[half];
                const f32x4* w0 = (const f32x4*)(Wt1 + (0 * HD1 + l) * SD);
                const f32x4* w1 = (const f32x4*)(Wt1 + (1 * HD1 + l) * SD);
                const f32x4* w2 = (const f32x4*)(Wt1 + (2 * HD1 + l) * SD);
                float acc = loadF(b1, l, bf);
#pragma unroll 4
                for (int jq = 0; jq < SD / 4; ++jq) {
                    f32x4 a = Av[jq], bb = Bv[jq], c = Cv[jq];
                    f32x4 x0 = w0[jq], x1 = w1[jq], x2 = w2[jq];
#pragma unroll
                    for (int q = 0; q < 4; ++q)
                        acc += a[q] * x0[q] + bb[q] * x1[q] + c[q] * x2[q];
                }
                H1[(long)r * HD1 + l] = tanhf(acc);
            }
            __syncthreads();
        }
    }
    gbar(barf, bargo, 6);

    // ---- S6: U1 = Lhat H1 -> T1 (60-stride) ----
    {
        int g = gtid >> 6, l = gtid & 63;
        if (l < HD1) {
            for (int r = g; r < NN; r += NTH / 64) {
                int beg = row_ptr[r], end = row_ptr[r + 1];
                float acc = 0.f;
                int p = beg;
                for (; p + 3 < end; p += 4) {
                    int2 e0 = csr[p], e1 = csr[p + 1], e2 = csr[p + 2], e3 = csr[p + 3];
                    acc += __int_as_float(e0.y) * H1[(long)e0.x * HD1 + l] +
                           __int_as_float(e1.y) * H1[(long)e1.x * HD1 + l] +
                           __int_as_float(e2.y) * H1[(long)e2.x * HD1 + l] +
                           __int_as_float(e3.y) * H1[(long)e3.x * HD1 + l];
                }
                for (; p < end; ++p) {
                    int2 e = csr[p];
                    acc += __int_as_float(e.y) * H1[(long)e.x * HD1 + l];
                }
                T1[(long)r * HD1 + l] = acc;
            }
        }
    }
    gbar(barf, bargo, 7);

    // ---- S7: T2' (LDS) + cheb2 -> H2  (uniform 5 iters, 64-thread groups) ----
    {
        int q4 = tid >> 6, l = tid & 63;
        int g = gid * 4 + q4;
        for (int it = 0; it < 5; ++it) {
            int r = g + it * 2048;
            bool act = r < NN;
            if (act && l < HD1) {
                float a0 = H1[(long)r * HD1 + l];
                tA[q4][l] = a0;
                tB[q4][l] = T1[(long)r * HD1 + l];
                int beg = row_ptr[r], end = row_ptr[r + 1];
                float acc = 0.f;
                int p = beg;
                for (; p + 3 < end; p += 4) {
                    int2 e0 = csr[p], e1 = csr[p + 1], e2 = csr[p + 2], e3 = csr[p + 3];
                    acc += __int_as_float(e0.y) * T1[(long)e0.x * HD1 + l] +
                           __int_as_float(e1.y) * T1[(long)e1.x * HD1 + l] +
                           __int_as_float(e2.y) * T1[(long)e2.x * HD1 + l] +
                           __int_as_float(e3.y) * T1[(long)e3.x * HD1 + l];
                }
                for (; p < end; ++p) {
                    int2 e = csr[p];
                    acc += __int_as_float(e.y) * T1[(long)e.x * HD1 + l];
                }
                tC[q4][l] = 2.f * acc - a0;
            }
            __syncthreads();
            if (act && l < HD2) {
                const f32x4* Av = (const f32x4*)tA[q4];
                const f32x4* Bv = (const f32x4*)tB[q4];
                const f32x4* Cv = (const f32x4*)tC[q4];
                const f32x4* w0 = (const f32x4*)(Wt2 + (0 * HD2 + l) * HD1);
                const f32x4* w1 = (const f32x4*)(Wt2 + (1 * HD2 + l) * HD1);
                const f32x4* w2 = (const f32x4*)(Wt2 + (2 * HD2 + l) * HD1);
                float acc = loadF(b2, l, bf);
#pragma unroll
                for (int jq = 0; jq < HD1 / 4; ++jq) {
                    f32x4 a = Av[jq], bb = Bv[jq], c = Cv[jq];
                    f32x4 x0 = w0[jq], x1 = w1[jq], x2 = w2[jq];
#pragma unroll
                    for (int q = 0; q < 4; ++q)
                        acc += a[q] * x0[q] + bb[q] * x1[q] + c[q] * x2[q];
                }
                H2[(long)r * HD2 + l] = tanhf(acc);
            }
            __syncthreads();
        }
    }
    gbar(barf, bargo, 8);

    // ---- S8: V1 = Lhat H2 -> T1 (30-stride) ----
    {
        int g = gtid >> 5, l = gtid & 31;
        if (l < HD2) {
            for (int r = g; r < NN; r += NTH / 32) {
                int beg = row_ptr[r], end = row_ptr[r + 1];
                float acc = 0.f;
                for (int p = beg; p < end; ++p) {
                    int2 e = csr[p];
                    acc += __int_as_float(e.y) * H2[(long)e.x * HD2 + l];
                }
                T1[(long)r * HD2 + l] = acc;
            }
        }
    }
    gbar(barf, bargo, 9);

    // ---- S9: V2 + cheb3 -> state[0..9999]; tail scalars ----
    {
        int g = gtid >> 5, l = gtid & 31;
        for (int r = g; r < NN; r += NTH / 32) {
            float contrib = 0.f;
            if (l < HD2) {
                float t0 = H2[(long)r * HD2 + l];
                float t1v = T1[(long)r * HD2 + l];
                int beg = row_ptr[r], end = row_ptr[r + 1];
                float acc = 0.f;
                for (int p = beg; p < end; ++p) {
                    int2 e = csr[p];
                    acc += __int_as_float(e.y) * T1[(long)e.x * HD2 + l];
                }
                float t2 = 2.f * acc - t0;
                contrib = t0 * Wt3[l] + t1v * Wt3[HD2 + l] + t2 * Wt3[2 * HD2 + l];
            }
#pragma unroll
            for (int m = 16; m; m >>= 1) contrib += __shfl_xor(contrib, m, 32);
            if (l == 0) state[r] = tanhf(contrib + loadF(b3, 0, bf));
        }
        if (gtid == 0) {
            state[10000] = loadF(sc0, 0, bf);
            state[10001] = loadF(sc1, 0, bf);
            state[10002] = loadF(sc2, 0, bf);
        }
    }
    gbar(barf, bargo, 10);

    // ---- S10: heads (wave per row, grid-stride) ----
    {
        int wv = gtid >> 6, lane = tid & 63;
        for (int r = wv; r <= ACT; r += NTH / 64) {
            long base = (r < ACT) ? (long)r * CONCAT : 0;
            const void* wb = (r < ACT) ? Wa : Wc;
            float acc = 0.f;
            if (bf) {
                const u16* w = (const u16*)wb + base;
                int k = (int)((16 - ((2 * base) & 15)) & 15) >> 1;
                for (int i = lane; i < k; i += 64) acc += state[i] * bf2f_bits(w[i]);
                int nv = (CONCAT - k) >> 3;
                const u16x8* wvp = (const u16x8*)(w + k);
                for (int v = lane; v < nv; v += 64) {
                    u16x8 ww = wvp[v];
                    int ib = k + v * 8;
#pragma unroll
                    for (int j = 0; j < 8; ++j) acc += state[ib + j] * bf2f_bits(ww[j]);
                }
                for (int i = k + nv * 8 + lane; i < CONCAT; i += 64)
                    acc += state[i] * bf2f_bits(w[i]);
            } else {
                const float* w = (const float*)wb + base;
                int k = (int)((16 - ((4 * base) & 15)) & 15) >> 2;
                for (int i = lane; i < k; i += 64) acc += state[i] * w[i];
                int nv = (CONCAT - k) >> 2;
                const f32x4* wvp = (const f32x4*)(w + k);
                for (int v = lane; v < nv; v += 64) {
                    f32x4 ww = wvp[v];
                    int ib = k + v * 4;
#pragma unroll
                    for (int j = 0; j < 4; ++j) acc += state[ib + j] * ww[j];
                }
                for (int i = k + nv * 4 + lane; i < CONCAT; i += 64)
                    acc += state[i] * w[i];
            }
#pragma unroll
            for (int o = 32; o > 0; o >>= 1) acc += __shfl_xor(acc, o);
            if (lane == 0) {
                float bias = (r < ACT) ? loadF(ba, r, bf) : loadF(bc, 0, bf);
                float v = acc + bias;
                if (bf) ((__hip_bfloat16*)out)[r] = __float2bfloat16(v);
                else ((float*)out)[r] = v;
            }
        }
    }
}

extern "C" void kernel_launch(void* const* d_in, const int* in_sizes, int n_in,
                              void* d_out, int out_size, void* d_ws, size_t ws_size,
                              hipStream_t stream) {
    char* p = (char*)d_ws;
    auto alloc = [&](size_t bytes) {
        char* r = p;
        p += (bytes + 255) & ~(size_t)255;
        return (void*)r;
    };
    int* barf = (int*)alloc(GRID * 4);
    int* bargo = (int*)alloc(4);
    int* deg = (int*)alloc(NN * 4);
    float* dinv = (float*)alloc(NN * 4);
    int* row_ptr = (int*)alloc((NN + 1) * 4);
    int* fillp = (int*)alloc(NN * 4);
    int2* csr = (int2*)alloc((size_t)NE * 8);
    float* X0 = (float*)alloc((size_t)NN * SD * 4);
    float* T1 = (float*)alloc((size_t)NN * SD * 4);
    float* H1 = (float*)alloc((size_t)NN * HD1 * 4);
    float* H2 = (float*)alloc((size_t)NN * HD2 * 4);
    float* Wt1 = (float*)alloc(3 * SD * HD1 * 4);
    float* Wt2 = (float*)alloc(3 * HD1 * HD2 * 4);
    float* Wt3 = (float*)alloc(3 * HD2 * 4);
    float* state = (float*)alloc(CONCAT * 4);

    mega<<<GRID, BS, 0, stream>>>(
        d_in[0], d_in[1], d_in[2], d_in[3], d_in[4], d_in[5], d_in[6], d_in[7],
        d_in[8], d_in[9], d_in[10], d_in[11], d_in[12], d_in[13], d_in[14],
        barf, bargo, deg, dinv, row_ptr, fillp, csr, X0, T1, H1, H2,
        Wt1, Wt2, Wt3, state, d_out);
}

// Round 8
// 651.621 us; speedup vs baseline: 5.2612x; 1.3746x over previous
//
#include <hip/hip_runtime.h>
#include <hip/hip_bf16.h>

#define NN 10000
#define NE 640000
#define SD 128
#define HD1 60
#define HD2 30
#define CONCAT 10003
#define ACT 10000
#define GRID 1024
#define BS 256
#define NTH (GRID * BS)
#define NWAVE (NTH / 64)

typedef unsigned int u32;
typedef unsigned short u16;
typedef u16 u16x8 __attribute__((ext_vector_type(8)));
typedef float f32x4 __attribute__((ext_vector_type(4)));

__device__ __forceinline__ float bf2f_bits(u16 u) {
    return __uint_as_float(((u32)u) << 16);
}
__device__ __forceinline__ float loadF(const void* base, long idx, int bf) {
    if (bf) return bf2f_bits(((const u16*)base)[idx]);
    return ((const float*)base)[idx];
}
__device__ __forceinline__ int loadI(const void* base, long idx, int i64) {
    if (i64) return (int)((const long long*)base)[idx];
    return ((const int*)base)[idx];
}

// poison-tolerant grid barrier: relaxed polls, one release fence before flag
// store, one acquire fence after go. (R6-validated protocol; R7 validated
// 1024-block exact-fit residency — rows<4096 were all correct.)
__device__ __forceinline__ void gbar(int* barf, int* bargo, int seq) {
    __syncthreads();
    if (threadIdx.x == 0) {
        __builtin_amdgcn_fence(__ATOMIC_RELEASE, "agent");
        __hip_atomic_store(&barf[blockIdx.x], seq, __ATOMIC_RELAXED, __HIP_MEMORY_SCOPE_AGENT);
    }
    if (blockIdx.x == 0) {
        __shared__ int sdone;
        int it = 0;
        while (true) {
            if (threadIdx.x == 0) sdone = 1;
            __syncthreads();
            int ok = 1;
            for (int b = threadIdx.x; b < GRID; b += BS) {
                if (__hip_atomic_load(&barf[b], __ATOMIC_RELAXED, __HIP_MEMORY_SCOPE_AGENT) != seq)
                    ok = 0;
            }
            if (!ok) sdone = 0;
            __syncthreads();
            if (sdone != 0 || ++it > (1 << 20)) break;
            __builtin_amdgcn_s_sleep(2);
        }
        if (threadIdx.x == 0)
            __hip_atomic_store(bargo, seq, __ATOMIC_RELAXED, __HIP_MEMORY_SCOPE_AGENT);
    } else if (threadIdx.x == 0) {
        int it = 0;
        while (__hip_atomic_load(bargo, __ATOMIC_RELAXED, __HIP_MEMORY_SCOPE_AGENT) != seq) {
            if (++it > (1 << 20)) break;
            __builtin_amdgcn_s_sleep(4);
        }
    }
    if (threadIdx.x == 0)
        __builtin_amdgcn_fence(__ATOMIC_ACQUIRE, "agent");
    __syncthreads();
}

__global__ void __launch_bounds__(BS, 4) mega(
    const void* __restrict__ x_in, const void* __restrict__ edge,
    const void* sc0, const void* sc1, const void* sc2,
    const void* __restrict__ W1, const void* __restrict__ b1,
    const void* __restrict__ W2, const void* __restrict__ b2,
    const void* __restrict__ W3, const void* __restrict__ b3,
    const void* __restrict__ Wa, const void* __restrict__ ba,
    const void* __restrict__ Wc, const void* __restrict__ bc,
    int* barf, int* bargo, int* __restrict__ deg, float* __restrict__ dinv,
    int* __restrict__ row_ptr, int* __restrict__ fillp, int2* __restrict__ csr,
    float* __restrict__ P0, float* __restrict__ P1, float* __restrict__ P2,
    float* __restrict__ Wv, float* __restrict__ Q0, float* __restrict__ Q1,
    float* __restrict__ Q2, float* __restrict__ Wv2, float* __restrict__ R1,
    float* __restrict__ R2, float* __restrict__ Sa, float* __restrict__ Wv3,
    float* __restrict__ state, void* __restrict__ out) {
    __shared__ int sflags[2];
    __shared__ int scan_lds[BS];

    const int tid = threadIdx.x, gid = blockIdx.x;
    const int gtid = gid * BS + tid;
    const int lane = tid & 63;
    const int wid = gtid >> 6;

    // per-block dtype probe
    if (tid == 0) {
        const int* e32 = (const int*)edge;
        int cnt64 = 0;
        for (int e = 0; e < 64; ++e) {
            int lo = e32[2 * e], hi = e32[2 * e + 1];
            if (hi == 0 && lo >= 0 && lo < NN) cnt64++;
        }
        sflags[0] = (cnt64 >= 56) ? 1 : 0;
        const u32* w = (const u32*)Wa;
        int c = 0;
        for (int j = 0; j < 256; ++j) {
            u32 lo = w[j] & 0xFFFFu;
            int ex = (int)((lo >> 7) & 0xFF);
            if (ex >= 100 && ex <= 140) c++;
        }
        sflags[1] = (c >= 128) ? 1 : 0;
    }
    __syncthreads();
    const int i64f = sflags[0], bf = sflags[1];

    // ---- S0: zero deg; project P_k = X @ W1[k]  (N x 60 each) ----
    for (int i = gtid; i < NN; i += NTH) deg[i] = 0;
    {
        int o = lane < 60 ? lane : 59;
        for (int r = wid; r < NN; r += NWAVE) {
            float xa, xb;
            if (bf) {
                u32 wbits = ((const u32*)x_in)[(long)r * 64 + lane];
                xa = bf2f_bits((u16)(wbits & 0xFFFFu));
                xb = bf2f_bits((u16)(wbits >> 16));
            } else {
                const float* xp = (const float*)x_in + (long)r * SD + 2 * lane;
                xa = xp[0];
                xb = xp[1];
            }
            float a0 = 0.f, a1 = 0.f, a2 = 0.f;
            for (int j2 = 0; j2 < 64; ++j2) {
                float xe = __shfl(xa, j2);
                float xo = __shfl(xb, j2);
                long je = (long)(2 * j2) * 60 + o;
                long jo = (long)(2 * j2 + 1) * 60 + o;
                a0 += xe * loadF(W1, 0 * SD * 60 + je, bf) + xo * loadF(W1, 0 * SD * 60 + jo, bf);
                a1 += xe * loadF(W1, 1 * SD * 60 + je, bf) + xo * loadF(W1, 1 * SD * 60 + jo, bf);
                a2 += xe * loadF(W1, 2 * SD * 60 + je, bf) + xo * loadF(W1, 2 * SD * 60 + jo, bf);
            }
            if (lane < 60) {
                P0[(long)r * 60 + lane] = a0;
                P1[(long)r * 60 + lane] = a1;
                P2[(long)r * 60 + lane] = a2;
            }
        }
    }
    gbar(barf, bargo, 1);

    // ---- S1: degree histogram ----
    for (int e = gtid; e < NE; e += NTH)
        atomicAdd(&deg[loadI(edge, NE + e, i64f)], 1);
    gbar(barf, bargo, 2);

    // ---- S2: dinv + scan (block 0) ----
    for (int i = gtid; i < NN; i += NTH) {
        int d = deg[i];
        dinv[i] = d > 0 ? rsqrtf((float)d) : 0.f;
    }
    if (gid == 0) {
        const int CH = 40;
        int base = tid * CH;
        int ssum = 0;
        for (int j = 0; j < CH; ++j) {
            int idx = base + j;
            if (idx < NN) ssum += deg[idx];
        }
        scan_lds[tid] = ssum;
        __syncthreads();
        for (int off = 1; off < BS; off <<= 1) {
            int t = (tid >= off) ? scan_lds[tid - off] : 0;
            __syncthreads();
            scan_lds[tid] += t;
            __syncthreads();
        }
        int run = (tid > 0) ? scan_lds[tid - 1] : 0;
        for (int j = 0; j < CH; ++j) {
            int idx = base + j;
            if (idx < NN) {
                row_ptr[idx] = run;
                fillp[idx] = run;
                run += deg[idx];
            }
        }
        if (tid == 255) row_ptr[NN] = scan_lds[255];
    }
    gbar(barf, bargo, 3);

    // ---- S3: CSR fill ----
    for (int e = gtid; e < NE; e += NTH) {
        int s = loadI(edge, e, i64f);
        int d = loadI(edge, NE + e, i64f);
        int pos = atomicAdd(&fillp[d], 1);
        int2 rec;
        rec.x = s;
        rec.y = __float_as_int(-dinv[s] * dinv[d]);
        csr[pos] = rec;
    }
    gbar(barf, bargo, 4);

    // ---- S4: U = Lhat P2 ; Wv = P1 + 2U   (wave/row, 60-wide, unroll 8) ----
    {
        int o = lane < 60 ? lane : 59;
        for (int r = wid; r < NN; r += NWAVE) {
            int beg = row_ptr[r], end = row_ptr[r + 1];
            float acc = 0.f;
            int p = beg;
            for (; p + 7 < end; p += 8) {
                float s = 0.f;
#pragma unroll
                for (int q = 0; q < 8; ++q) {
                    int2 e = csr[p + q];
                    s += __int_as_float(e.y) * P2[(long)e.x * 60 + o];
                }
                acc += s;
            }
            for (; p < end; ++p) {
                int2 e = csr[p];
                acc += __int_as_float(e.y) * P2[(long)e.x * 60 + o];
            }
            if (lane < 60)
                Wv[(long)r * 60 + lane] = P1[(long)r * 60 + lane] + 2.f * acc;
        }
    }
    gbar(barf, bargo, 5);

    // ---- S5: V = Lhat Wv ; h1 = tanh(P0-P2+V+b1); Q_k = h1 @ W2[k] ----
    {
        int o = lane < 60 ? lane : 59;
        int o2 = lane < 30 ? lane : 29;
        for (int r = wid; r < NN; r += NWAVE) {
            int beg = row_ptr[r], end = row_ptr[r + 1];
            float acc = 0.f;
            int p = beg;
            for (; p + 7 < end; p += 8) {
                float s = 0.f;
#pragma unroll
                for (int q = 0; q < 8; ++q) {
                    int2 e = csr[p + q];
                    s += __int_as_float(e.y) * Wv[(long)e.x * 60 + o];
                }
                acc += s;
            }
            for (; p < end; ++p) {
                int2 e = csr[p];
                acc += __int_as_float(e.y) * Wv[(long)e.x * 60 + o];
            }
            float h1 = tanhf(P0[(long)r * 60 + o] - P2[(long)r * 60 + o] + acc +
                             loadF(b1, o, bf));
            float q0 = 0.f, q1 = 0.f, q2 = 0.f;
            for (int j = 0; j < 60; ++j) {
                float xj = __shfl(h1, j);
                long idx = (long)j * 30 + o2;
                q0 += xj * loadF(W2, 0 * 60 * 30 + idx, bf);
                q1 += xj * loadF(W2, 1 * 60 * 30 + idx, bf);
                q2 += xj * loadF(W2, 2 * 60 * 30 + idx, bf);
            }
            if (lane < 30) {
                Q0[(long)r * 30 + lane] = q0;
                Q1[(long)r * 30 + lane] = q1;
                Q2[(long)r * 30 + lane] = q2;
            }
        }
    }
    gbar(barf, bargo, 6);

    // ---- S6: U2 = Lhat Q2 ; Wv2 = Q1 + 2U2  (half-wave edges, 30-wide) ----
    {
        int h = lane >> 5, l = lane & 31;
        int l2 = l < 30 ? l : 29;
        for (int r = wid; r < NN; r += NWAVE) {
            int beg = row_ptr[r], end = row_ptr[r + 1];
            float acc = 0.f;
            int p = beg + h;
            for (; p + 7 < end; p += 8) {
#pragma unroll
                for (int q = 0; q < 8; q += 2) {
                    int2 e = csr[p + q];
                    acc += __int_as_float(e.y) * Q2[(long)e.x * 30 + l2];
                }
            }
            for (; p < end; p += 2) {
                int2 e = csr[p];
                acc += __int_as_float(e.y) * Q2[(long)e.x * 30 + l2];
            }
            acc += __shfl_xor(acc, 32);
            if (lane < 30)
                Wv2[(long)r * 30 + lane] = Q1[(long)r * 30 + lane] + 2.f * acc;
        }
    }
    gbar(barf, bargo, 7);

    // ---- S7: V2 = Lhat Wv2 ; h2 = tanh(Q0-Q2+V2+b2); R_k = h2 . W3[k] ----
    {
        int h = lane >> 5, l = lane & 31;
        int l2 = l < 30 ? l : 29;
        for (int r = wid; r < NN; r += NWAVE) {
            int beg = row_ptr[r], end = row_ptr[r + 1];
            float acc = 0.f;
            int p = beg + h;
            for (; p + 7 < end; p += 8) {
#pragma unroll
                for (int q = 0; q < 8; q += 2) {
                    int2 e = csr[p + q];
                    acc += __int_as_float(e.y) * Wv2[(long)e.x * 30 + l2];
                }
            }
            for (; p < end; p += 2) {
                int2 e = csr[p];
                acc += __int_as_float(e.y) * Wv2[(long)e.x * 30 + l2];
            }
            acc += __shfl_xor(acc, 32);
            float r0 = 0.f, r1 = 0.f, r2 = 0.f;
            if (l < 30) {
                float h2v = tanhf(Q0[(long)r * 30 + l] - Q2[(long)r * 30 + l] + acc +
                                  loadF(b2, l, bf));
                r0 = h2v * loadF(W3, 0 * 30 + l, bf);
                r1 = h2v * loadF(W3, 1 * 30 + l, bf);
                r2 = h2v * loadF(W3, 2 * 30 + l, bf);
            }
#pragma unroll
            for (int m = 16; m; m >>= 1) {
                r0 += __shfl_xor(r0, m);
                r1 += __shfl_xor(r1, m);
                r2 += __shfl_xor(r2, m);
            }
            if (lane == 0) {
                R1[r] = r1;
                R2[r] = r2;
                Sa[r] = r0 - r2;
            }
        }
    }
    gbar(barf, bargo, 8);

    // ---- S8: U3 = Lhat R2 ; Wv3 = R1 + 2U3  (lanes over edges) ----
    {
        for (int r = wid; r < NN; r += NWAVE) {
            int beg = row_ptr[r], end = row_ptr[r + 1];
            float acc = 0.f;
            for (int p = beg + lane; p < end; p += 64) {
                int2 e = csr[p];
                acc += __int_as_float(e.y) * R2[e.x];
            }
#pragma unroll
            for (int m = 32; m; m >>= 1) acc += __shfl_xor(acc, m);
            if (lane == 0) Wv3[r] = R1[r] + 2.f * acc;
        }
    }
    gbar(barf, bargo, 9);

    // ---- S9: V3 = Lhat Wv3 ; state = tanh(Sa + V3 + b3) ----
    {
        for (int r = wid; r < NN; r += NWAVE) {
            int beg = row_ptr[r], end = row_ptr[r + 1];
            float acc = 0.f;
            for (int p = beg + lane; p < end; p += 64) {
                int2 e = csr[p];
                acc += __int_as_float(e.y) * Wv3[e.x];
            }
#pragma unroll
            for (int m = 32; m; m >>= 1) acc += __shfl_xor(acc, m);
            if (lane == 0) state[r] = tanhf(Sa[r] + acc + loadF(b3, 0, bf));
        }
        if (gtid == 0) {
            state[10000] = loadF(sc0, 0, bf);
            state[10001] = loadF(sc1, 0, bf);
            state[10002] = loadF(sc2, 0, bf);
        }
    }
    gbar(barf, bargo, 10);

    // ---- S10: heads (wave per row, grid-stride — R7 bug was a missing loop) ----
    {
        for (int r = wid; r <= ACT; r += NWAVE) {
            long base = (r < ACT) ? (long)r * CONCAT : 0;
            const void* wb = (r < ACT) ? Wa : Wc;
            float acc = 0.f;
            if (bf) {
                const u16* w = (const u16*)wb + base;
                int k = (int)((16 - ((2 * base) & 15)) & 15) >> 1;
                for (int i = lane; i < k; i += 64) acc += state[i] * bf2f_bits(w[i]);
                int nv = (CONCAT - k) >> 3;
                const u16x8* wvp = (const u16x8*)(w + k);
                for (int v = lane; v < nv; v += 64) {
                    u16x8 ww = wvp[v];
                    int ib = k + v * 8;
#pragma unroll
                    for (int j = 0; j < 8; ++j) acc += state[ib + j] * bf2f_bits(ww[j]);
                }
                for (int i = k + nv * 8 + lane; i < CONCAT; i += 64)
                    acc += state[i] * bf2f_bits(w[i]);
            } else {
                const float* w = (const float*)wb + base;
                int k = (int)((16 - ((4 * base) & 15)) & 15) >> 2;
                for (int i = lane; i < k; i += 64) acc += state[i] * w[i];
                int nv = (CONCAT - k) >> 2;
                const f32x4* wvp = (const f32x4*)(w + k);
                for (int v = lane; v < nv; v += 64) {
                    f32x4 ww = wvp[v];
                    int ib = k + v * 4;
#pragma unroll
                    for (int j = 0; j < 4; ++j) acc += state[ib + j] * ww[j];
                }
                for (int i = k + nv * 4 + lane; i < CONCAT; i += 64)
                    acc += state[i] * w[i];
            }
#pragma unroll
            for (int o = 32; o > 0; o >>= 1) acc += __shfl_xor(acc, o);
            if (lane == 0) {
                float bias = (r < ACT) ? loadF(ba, r, bf) : loadF(bc, 0, bf);
                float v = acc + bias;
                if (bf) ((__hip_bfloat16*)out)[r] = __float2bfloat16(v);
                else ((float*)out)[r] = v;
            }
        }
    }
}

extern "C" void kernel_launch(void* const* d_in, const int* in_sizes, int n_in,
                              void* d_out, int out_size, void* d_ws, size_t ws_size,
                              hipStream_t stream) {
    char* p = (char*)d_ws;
    auto alloc = [&](size_t bytes) {
        char* r = p;
        p += (bytes + 255) & ~(size_t)255;
        return (void*)r;
    };
    int* barf = (int*)alloc(GRID * 4);
    int* bargo = (int*)alloc(4);
    int* deg = (int*)alloc(NN * 4);
    float* dinv = (float*)alloc(NN * 4);
    int* row_ptr = (int*)alloc((NN + 1) * 4);
    int* fillp = (int*)alloc(NN * 4);
    int2* csr = (int2*)alloc((size_t)NE * 8);
    float* P0 = (float*)alloc((size_t)NN * 60 * 4);
    float* P1 = (float*)alloc((size_t)NN * 60 * 4);
    float* P2 = (float*)alloc((size_t)NN * 60 * 4);
    float* Wv = (float*)alloc((size_t)NN * 60 * 4);
    float* Q0 = (float*)alloc((size_t)NN * 30 * 4);
    float* Q1 = (float*)alloc((size_t)NN * 30 * 4);
    float* Q2 = (float*)alloc((size_t)NN * 30 * 4);
    float* Wv2 = (float*)alloc((size_t)NN * 30 * 4);
    float* R1 = (float*)alloc(NN * 4);
    float* R2 = (float*)alloc(NN * 4);
    float* Sa = (float*)alloc(NN * 4);
    float* Wv3 = (float*)alloc(NN * 4);
    float* state = (float*)alloc(CONCAT * 4);

    mega<<<GRID, BS, 0, stream>>>(
        d_in[0], d_in[1], d_in[2], d_in[3], d_in[4], d_in[5], d_in[6], d_in[7],
        d_in[8], d_in[9], d_in[10], d_in[11], d_in[12], d_in[13], d_in[14],
        barf, bargo, deg, dinv, row_ptr, fillp, csr,
        P0, P1, P2, Wv, Q0, Q1, Q2, Wv2, R1, R2, Sa, Wv3, state, d_out);
}